// Round 9
// baseline (262.099 us; speedup 1.0000x reference)
//
#include <hip/hip_runtime.h>

#define CH 32        // events per chunk
#define NCHUNK 32    // 1024 / CH
#define NE 1024
#define DH 400
#define DIN 784
#define PF 8         // W1-row prefetch depth
#define NTHR 1024    // 16 waves: 0-6 LIF, 7-14 extract, 15 consume

// TAU = -1/ln(0.2) as the reference's Python double, rounded to f32
#define TAUF ((float)0.6213349345596119)

__global__ void prep_transpose(const float* __restrict__ W1, float* __restrict__ W1T) {
  int idx = blockIdx.x * 256 + threadIdx.x;
  const int total = DIN * DH;
  if (idx < total) {
    int p = idx / DH;
    int j = idx - p * DH;
    W1T[idx] = W1[j * DIN + p];
  } else if (idx < total + 64) {
    W1T[idx] = 0.0f;
  }
}

#define STEP(WV)                                   \
  do {                                             \
    float mn_ = __fadd_rn(h2, (WV));               \
    bool f_ = (mn_ >= 0.5f);                       \
    cntf = f_ ? (cntf + 1.0f) : cntf;              \
    h2 = f_ ? 0.0f : mn_;                          \
  } while (0)

#define SPEC8(W0, W1, W2, W3, W4, W5, W6, W7)                                  \
  do {                                                                         \
    float q0f = __fadd_rn(h2, (W0));                                           \
    float q1f = __fadd_rn(q0f, (W1));                                          \
    float q2f = __fadd_rn(q1f, (W2));                                          \
    float q3f = __fadd_rn(q2f, (W3));                                          \
    float q4f = __fadd_rn(q3f, (W4));                                          \
    float q5f = __fadd_rn(q4f, (W5));                                          \
    float q6f = __fadd_rn(q5f, (W6));                                          \
    float q7f = __fadd_rn(q6f, (W7));                                          \
    bool anyF = (q0f >= 0.5f) | (q1f >= 0.5f) | (q2f >= 0.5f) | (q3f >= 0.5f) |\
                (q4f >= 0.5f) | (q5f >= 0.5f) | (q6f >= 0.5f) | (q7f >= 0.5f); \
    if (!anyF) {                                                               \
      h2 = q7f;                                                                \
    } else {                                                                   \
      STEP(W0); STEP(W1); STEP(W2); STEP(W3);                                  \
      STEP(W4); STEP(W5); STEP(W6); STEP(W7);                                  \
    }                                                                          \
  } while (0)

#define WSEL(PW, CW, WB)                            \
  do {                                              \
    bool c_ = (N >= (PW));                          \
    q = c_ ? (CW) : q;                              \
    r = c_ ? (N - (PW)) : r;                        \
    wb = c_ ? (WB) : wb;                            \
  } while (0)

#define RSEL64()                                                               \
  unsigned lo = (unsigned)q, hi = (unsigned)(q >> 32);                         \
  unsigned pc = (unsigned)__popc(lo);                                          \
  bool gg = r >= pc; unsigned base = gg ? 32u : 0u;                            \
  unsigned x = gg ? hi : lo; r = gg ? r - pc : r;                              \
  pc = (unsigned)__popc(x & 0xFFFFu); gg = r >= pc; base += gg ? 16u : 0u;     \
  x = gg ? (x >> 16) : (x & 0xFFFFu); r = gg ? r - pc : r;                     \
  pc = (unsigned)__popc(x & 0xFFu); gg = r >= pc; base += gg ? 8u : 0u;        \
  x = gg ? (x >> 8) : (x & 0xFFu); r = gg ? r - pc : r;                        \
  pc = (unsigned)__popc(x & 0xFu); gg = r >= pc; base += gg ? 4u : 0u;         \
  x = gg ? (x >> 4) : (x & 0xFu); r = gg ? r - pc : r;                         \
  pc = (unsigned)__popc(x & 0x3u); gg = r >= pc; base += gg ? 2u : 0u;         \
  x = gg ? (x >> 2) : (x & 0x3u); r = gg ? r - pc : r;                         \
  gg = r >= (x & 1u); base += gg ? 1u : 0u;

// build 7 uniform 64-bit masks from one lane-spread b64 read
#define LOADMASKS(MB, E)                                                       \
  uint2 mw = *reinterpret_cast<const uint2*>(&s_masksT[MB][lane & 7][E]);      \
  unsigned long long c0 =                                                      \
      ((unsigned long long)(unsigned)__builtin_amdgcn_readlane(mw.y, 0) << 32) |\
      (unsigned)__builtin_amdgcn_readlane(mw.x, 0);                            \
  unsigned long long c1 =                                                      \
      ((unsigned long long)(unsigned)__builtin_amdgcn_readlane(mw.y, 1) << 32) |\
      (unsigned)__builtin_amdgcn_readlane(mw.x, 1);                            \
  unsigned long long c2 =                                                      \
      ((unsigned long long)(unsigned)__builtin_amdgcn_readlane(mw.y, 2) << 32) |\
      (unsigned)__builtin_amdgcn_readlane(mw.x, 2);                            \
  unsigned long long c3 =                                                      \
      ((unsigned long long)(unsigned)__builtin_amdgcn_readlane(mw.y, 3) << 32) |\
      (unsigned)__builtin_amdgcn_readlane(mw.x, 3);                            \
  unsigned long long c4 =                                                      \
      ((unsigned long long)(unsigned)__builtin_amdgcn_readlane(mw.y, 4) << 32) |\
      (unsigned)__builtin_amdgcn_readlane(mw.x, 4);                            \
  unsigned long long c5 =                                                      \
      ((unsigned long long)(unsigned)__builtin_amdgcn_readlane(mw.y, 5) << 32) |\
      (unsigned)__builtin_amdgcn_readlane(mw.x, 5);                            \
  unsigned long long c6 =                                                      \
      ((unsigned long long)(unsigned)__builtin_amdgcn_readlane(mw.y, 6) << 32) |\
      (unsigned)__builtin_amdgcn_readlane(mw.x, 6);

__device__ __forceinline__ float rl_f(float v, int l) {
  return __int_as_float(__builtin_amdgcn_readlane(__float_as_int(v), l));
}

template <bool TR>
__global__ __launch_bounds__(NTHR, 4) void snn_main(
    const float* __restrict__ ET, const int* __restrict__ EP,
    const float* __restrict__ W1x, const float* __restrict__ b1,
    const float* __restrict__ W2, const float* __restrict__ b2,
    float* __restrict__ out) {
  __shared__ float s_W2c[401 * 16];                        // W2.T + b2/400; row 400 = zeros
  __shared__ __align__(16) unsigned long long s_masksT[3][8][CH + 2];  // [buf][wave][event]
  __shared__ float s_dec1[NE];
  __shared__ float s_dec2[NE];
  __shared__ int s_EP[NE];
  __shared__ __align__(16) int s_spklist[2][CH][64];       // ordered spike lists
  __shared__ __align__(16) float s_wlistT[2][CH][16 * 20]; // [comp*20 + slot], 16 slots
  __shared__ int s_spkcnt[2][CH];
  __shared__ __align__(16) int s_spk2[64];

  const int tid = threadIdx.x;
  const int b = blockIdx.x;
  const int eb = b * NE;

  for (int i = tid; i < 401 * 16; i += NTHR) {
    int row = i >> 4, col = i & 15;
    float v = 0.0f;
    if (row < DH && col < 10) v = __fadd_rn(W2[col * DH + row], __fdiv_rn(b2[col], 400.0f));
    s_W2c[i] = v;
  }
  for (int i = tid; i < NE; i += NTHR) {
    s_EP[i] = EP[eb + i];
    float t = ET[eb + i];
    float tp = (i > 0) ? ET[eb + i - 1] : 0.0f;
    s_dec1[i] = expf(__fdiv_rn(-(t - tp), TAUF));
    float th = __fadd_rn(t, 0.1f);
    float thp = (i > 0) ? __fadd_rn(tp, 0.1f) : 0.0f;
    s_dec2[i] = expf(__fdiv_rn(-(th - thp), TAUF));
  }

  const int lane = tid & 63;
  const int wv = tid >> 6;
  const bool isL1 = (wv < 7);          // stage-1 waves (LIF + ballot)
  const bool isEx = (wv >= 7 && wv < 15);  // stage-2 waves (extract + gather), 4 events each
  const bool isCons = (wv == 15);      // stage-3 wave
  const bool act = (tid < DH);

  float m1 = 0.0f;
  float b1v = act ? __fdiv_rn(b1[tid < DH ? tid : DH - 1], 784.0f) : 0.0f;
  float wp[PF];

  float h2 = 0.0f, cntf = 0.0f;
  const int kk = lane & 15;

  __syncthreads();

  if (isL1) {
#pragma unroll
    for (int i = 0; i < PF; ++i) {
      int p = s_EP[i];
      wp[i] = TR ? W1x[p * DH + tid] : W1x[(tid < DH ? tid : DH - 1) * DIN + p];
    }
  } else {
#pragma unroll
    for (int i = 0; i < PF; ++i) wp[i] = 0.0f;
  }

  // 3-stage pipeline on DISJOINT wave groups (concurrent between barriers):
  //   waves 0-6: produce chunk it | waves 7-14: extract chunk it-1 | wave 15: consume it-2
  for (int it = 0; it <= NCHUNK + 1; ++it) {
    if (isL1) {
      // ---- stage 1: masks for chunk it ----
      if (it < NCHUNK) {
        const int mb = it % 3;
        const int gbase = it * CH;
        float decv = s_dec1[(gbase + lane) & (NE - 1)];
        int epv = s_EP[(gbase + 8 + lane) & (NE - 1)];
        unsigned long long balPrev = 0ull;
#pragma unroll
        for (int e = 0; e < CH; ++e) {
          float dv = rl_f(decv, e);                     // dec1[gbase+e] via readlane
          float mm = __fmul_rn(m1, dv);                 // exact ref order, no FMA
          mm = __fadd_rn(mm, wp[e & (PF - 1)]);
          mm = __fadd_rn(mm, b1v);
          bool fired = act && (mm >= 0.5f);
          unsigned long long bal = __ballot(fired);
          m1 = fired ? 0.0f : mm;
          if ((e & 1) == 0) {
            balPrev = bal;
          } else if (lane == 0) {                       // paired b128 write (2 events)
            ulonglong2 pr; pr.x = balPrev; pr.y = bal;
            *reinterpret_cast<ulonglong2*>(&s_masksT[mb][wv][e - 1]) = pr;
          }
          int pn = __builtin_amdgcn_readlane(epv, e);   // EP[gbase+e+8]
          wp[e & (PF - 1)] =
              TR ? W1x[pn * DH + tid] : W1x[(tid < DH ? tid : DH - 1) * DIN + pn];
        }
      }
    } else if (isEx) {
      // ---- stage 2: extract chunk it-1 (8 waves x 4 events, no remainder) ----
      if (it >= 1 && it <= NCHUNK) {
        const int c = it - 1;
        const int mb = c % 3;
        const int lb = c & 1;
        const int e0 = (wv - 7) * 4;
#pragma unroll
        for (int k = 0; k < 4; ++k) {
          const int e = e0 + k;
          LOADMASKS(mb, e);
          unsigned P1 = (unsigned)__popcll(c0);
          unsigned P2 = P1 + (unsigned)__popcll(c1);
          unsigned P3 = P2 + (unsigned)__popcll(c2);
          unsigned P4 = P3 + (unsigned)__popcll(c3);
          unsigned P5 = P4 + (unsigned)__popcll(c4);
          unsigned P6 = P5 + (unsigned)__popcll(c5);
          unsigned total = P6 + (unsigned)__popcll(c6);
          unsigned N = (unsigned)lane;
          unsigned long long q = c0;
          unsigned r = N, wb = 0;
          WSEL(P1, c1, 64);  WSEL(P2, c2, 128); WSEL(P3, c3, 192);
          WSEL(P4, c4, 256); WSEL(P5, c5, 320); WSEL(P6, c6, 384);
          RSEL64();
          int j = (int)(wb + base);
          j = (N < total) ? j : DH;                     // dummy zero-weight row
          s_spklist[lb][e][lane] = j;
          if (lane == 0) s_spkcnt[lb][e] = (int)total;
          // pre-gather: slots 0..7 always; 8..15 only if needed (uniform branch)
#pragma unroll
          for (int p = 0; p < 2; ++p) {
            int sl = p * 4 + (lane >> 4);
            int js = __builtin_amdgcn_ds_bpermute(sl << 2, j);
            float w = s_W2c[js * 16 + (lane & 15)];
            s_wlistT[lb][e][(lane & 15) * 20 + sl] = w;
          }
          if (total > 8) {
#pragma unroll
            for (int p = 2; p < 4; ++p) {
              int sl = p * 4 + (lane >> 4);
              int js = __builtin_amdgcn_ds_bpermute(sl << 2, j);
              float w = s_W2c[js * 16 + (lane & 15)];
              s_wlistT[lb][e][(lane & 15) * 20 + sl] = w;
            }
          }
        }
      }
    } else {
      // ---- stage 3: consume chunk it-2 (wave 15) ----
      if (isCons && it >= 2) {
        const int c = it - 2;
        const int lb = c & 1;
        const int mb = c % 3;
        const int gb2 = c * CH;
        int cntv = s_spkcnt[lb][lane & 31];
        float d2v = s_dec2[gb2 + (lane & 31)];

        auto loadEvt = [&](int ee, int& tot, float& cdv, float (&w)[16]) {
          tot = __builtin_amdgcn_readlane(cntv, ee);
          cdv = rl_f(d2v, ee);
          const float4* wrow = reinterpret_cast<const float4*>(&s_wlistT[lb][ee][kk * 20]);
          float4 a = wrow[0], b4 = wrow[1];
          w[0] = a.x; w[1] = a.y; w[2] = a.z; w[3] = a.w;
          w[4] = b4.x; w[5] = b4.y; w[6] = b4.z; w[7] = b4.w;
          if (tot > 8) {
            float4 c4 = wrow[2], d4 = wrow[3];
            w[8] = c4.x; w[9] = c4.y; w[10] = c4.z; w[11] = c4.w;
            w[12] = d4.x; w[13] = d4.y; w[14] = d4.z; w[15] = d4.w;
          }
        };
        auto procEvt = [&](int e, int tot, float cdv, float (&w)[16]) {
          h2 = __fmul_rn(h2, cdv);
          if (tot > 0) {
            SPEC8(w[0], w[1], w[2], w[3], w[4], w[5], w[6], w[7]);
            if (tot > 8) {
              SPEC8(w[8], w[9], w[10], w[11], w[12], w[13], w[14], w[15]);
            }
            if (tot > 16) {  // cold: remaining spikes from the list
              int lim = tot < 64 ? tot : 64;
              for (int dn = 16; dn < lim; dn += 8) {
                const int4* sp = (const int4*)(&s_spklist[lb][e][dn]);
                int4 ja = sp[0], jb = sp[1];
                float v0 = s_W2c[ja.x * 16 + kk];
                float v1 = s_W2c[ja.y * 16 + kk];
                float v2 = s_W2c[ja.z * 16 + kk];
                float v3 = s_W2c[ja.w * 16 + kk];
                float v4 = s_W2c[jb.x * 16 + kk];
                float v5 = s_W2c[jb.y * 16 + kk];
                float v6 = s_W2c[jb.z * 16 + kk];
                float v7 = s_W2c[jb.w * 16 + kk];
                SPEC8(v0, v1, v2, v3, v4, v5, v6, v7);
              }
              if (tot > 64) {  // colder: re-extract from still-live masks
                LOADMASKS(mb, e);
                unsigned P1 = (unsigned)__popcll(c0);
                unsigned P2 = P1 + (unsigned)__popcll(c1);
                unsigned P3 = P2 + (unsigned)__popcll(c2);
                unsigned P4 = P3 + (unsigned)__popcll(c3);
                unsigned P5 = P4 + (unsigned)__popcll(c4);
                unsigned P6 = P5 + (unsigned)__popcll(c5);
                for (int done = 64; done < tot; done += 64) {
                  unsigned N = (unsigned)(done + lane);
                  unsigned long long q = c0;
                  unsigned r = N, wb = 0;
                  WSEL(P1, c1, 64);  WSEL(P2, c2, 128); WSEL(P3, c3, 192);
                  WSEL(P4, c4, 256); WSEL(P5, c5, 320); WSEL(P6, c6, 384);
                  RSEL64();
                  int j = (int)(wb + base);
                  j = (N < (unsigned)tot) ? j : DH;
                  s_spk2[lane] = j;
                  int cnt = tot - done; cnt = cnt > 64 ? 64 : cnt;
                  int nb2 = (cnt + 7) >> 3;
                  for (int bb = 0; bb < nb2; ++bb) {
                    const int4* sp = (const int4*)(s_spk2 + bb * 8);
                    int4 ja = sp[0], jb = sp[1];
                    float v0 = s_W2c[ja.x * 16 + kk];
                    float v1 = s_W2c[ja.y * 16 + kk];
                    float v2 = s_W2c[ja.z * 16 + kk];
                    float v3 = s_W2c[ja.w * 16 + kk];
                    float v4 = s_W2c[jb.x * 16 + kk];
                    float v5 = s_W2c[jb.y * 16 + kk];
                    float v6 = s_W2c[jb.z * 16 + kk];
                    float v7 = s_W2c[jb.w * 16 + kk];
                    SPEC8(v0, v1, v2, v3, v4, v5, v6, v7);
                  }
                }
              }
            }
          }
        };

        int totA, totB; float cdA, cdB; float wA[16], wB[16];
        loadEvt(0, totA, cdA, wA);
        for (int e = 0; e < CH; e += 2) {
          loadEvt(e + 1, totB, cdB, wB);
          procEvt(e, totA, cdA, wA);
          if (e + 2 < CH) loadEvt(e + 2, totA, cdA, wA);
          procEvt(e + 1, totB, cdB, wB);
        }
      }
    }
    __syncthreads();
  }

  if (isCons && lane < 10) out[b * 10 + lane] = __fmul_rn(cntf, 0.015625f);
}

extern "C" void kernel_launch(void* const* d_in, const int* in_sizes, int n_in,
                              void* d_out, int out_size, void* d_ws, size_t ws_size,
                              hipStream_t stream) {
  const float* ET = (const float*)d_in[0];
  const int* EP = (const int*)d_in[1];
  const float* W1 = (const float*)d_in[2];
  const float* b1 = (const float*)d_in[3];
  const float* W2 = (const float*)d_in[4];
  const float* b2 = (const float*)d_in[5];
  float* out = (float*)d_out;

  const size_t need = (size_t)(DIN * DH + 64) * sizeof(float);
  if (ws_size >= need) {
    float* W1T = (float*)d_ws;
    hipLaunchKernelGGL(prep_transpose, dim3((DIN * DH + 64 + 255) / 256), dim3(256), 0, stream,
                       W1, W1T);
    hipLaunchKernelGGL((snn_main<true>), dim3(256), dim3(NTHR), 0, stream,
                       ET, EP, W1T, b1, W2, b2, out);
  } else {
    hipLaunchKernelGGL((snn_main<false>), dim3(256), dim3(NTHR), 0, stream,
                       ET, EP, W1, b1, W2, b2, out);
  }
}